// Round 1
// baseline (409.068 us; speedup 1.0000x reference)
//
#include <hip/hip_runtime.h>

// Problem constants (fixed by reference)
#define N_NODES 100000
#define N_EDGES 1000000
#define FDIM    64
#define ALPHA   0.1f
#define BETA    0.5f

#define SCAN_BLOCKS 391   // ceil(N_NODES/256)

// ws layout (byte offsets). Total ~38.2 MB.
#define OFF_DEG     0u          // N_NODES ints
#define OFF_OFFS    524288u     // N_NODES ints
#define OFF_CURSOR  1048576u    // N_NODES ints
#define OFF_BSUM    1572864u    // SCAN_BLOCKS ints
#define OFF_BOFF    1703936u    // SCAN_BLOCKS ints
#define OFF_BSRC    2097152u    // N_EDGES ints   (4 MB)
#define OFF_BVAL    6291456u    // N_EDGES floats (4 MB)
#define OFF_SUP     12582912u   // N_NODES*FDIM floats (25.6 MB)

__global__ void k_hist(const int* __restrict__ dst, int* __restrict__ deg) {
    int e = blockIdx.x * blockDim.x + threadIdx.x;
    if (e < N_EDGES) atomicAdd(&deg[dst[e]], 1);
}

__global__ void k_scan1(const int* __restrict__ deg, int* __restrict__ bsum) {
    __shared__ int lds[256];
    int i = blockIdx.x * 256 + threadIdx.x;
    int v = (i < N_NODES) ? deg[i] : 0;
    lds[threadIdx.x] = v;
    __syncthreads();
    for (int s = 128; s > 0; s >>= 1) {
        if (threadIdx.x < s) lds[threadIdx.x] += lds[threadIdx.x + s];
        __syncthreads();
    }
    if (threadIdx.x == 0) bsum[blockIdx.x] = lds[0];
}

// single block, 512 threads: exclusive scan of SCAN_BLOCKS block sums
__global__ void k_scan2(const int* __restrict__ bsum, int* __restrict__ boff) {
    __shared__ int lds[512];
    int t = threadIdx.x;
    int v = (t < SCAN_BLOCKS) ? bsum[t] : 0;
    lds[t] = v;
    __syncthreads();
    for (int off = 1; off < 512; off <<= 1) {
        int add = (t >= off) ? lds[t - off] : 0;
        __syncthreads();
        lds[t] += add;
        __syncthreads();
    }
    if (t < SCAN_BLOCKS) boff[t] = lds[t] - v;  // exclusive
}

__global__ void k_scan3(const int* __restrict__ deg, const int* __restrict__ boff,
                        int* __restrict__ offs, int* __restrict__ cursor) {
    __shared__ int lds[256];
    int t = threadIdx.x;
    int i = blockIdx.x * 256 + t;
    int v = (i < N_NODES) ? deg[i] : 0;
    lds[t] = v;
    __syncthreads();
    for (int off = 1; off < 256; off <<= 1) {
        int add = (t >= off) ? lds[t - off] : 0;
        __syncthreads();
        lds[t] += add;
        __syncthreads();
    }
    int excl = lds[t] - v + boff[blockIdx.x];
    if (i < N_NODES) { offs[i] = excl; cursor[i] = excl; }
}

__global__ void k_bin(const int* __restrict__ src, const int* __restrict__ dst,
                      const float* __restrict__ val, int* __restrict__ cursor,
                      int* __restrict__ bsrc, float* __restrict__ bval) {
    int e = blockIdx.x * blockDim.x + threadIdx.x;
    if (e >= N_EDGES) return;
    int d = dst[e];
    int p = atomicAdd(&cursor[d], 1);
    bsrc[p] = src[e];
    bval[p] = val[e];
}

// one wave per node; lane = feature index. Writes support = 0.9*hi + 0.1*f0.
__global__ void k_gather(const int* __restrict__ offs, const int* __restrict__ bsrc,
                         const float* __restrict__ bval, const float* __restrict__ feat,
                         const float* __restrict__ f0, float* __restrict__ sup) {
    int gid  = blockIdx.x * blockDim.x + threadIdx.x;
    int node = gid >> 6;
    int lane = threadIdx.x & 63;
    if (node >= N_NODES) return;
    int beg = offs[node];
    int end = (node == N_NODES - 1) ? N_EDGES : offs[node + 1];
    float acc = 0.0f;
    for (int e = beg; e < end; ++e) {
        int   s = bsrc[e];   // wave-uniform -> scalar load
        float v = bval[e];   // wave-uniform -> scalar load
        acc += v * feat[s * FDIM + lane];  // coalesced 256B/wave
    }
    sup[node * FDIM + lane] = (1.0f - ALPHA) * acc + ALPHA * f0[node * FDIM + lane];
}

// thread per node: out = relu(BETA*(s@W) + (1-BETA)*s)
__global__ void k_out(const float* __restrict__ sup, const float* __restrict__ W,
                      float* __restrict__ out) {
    int i = blockIdx.x * blockDim.x + threadIdx.x;
    if (i >= N_NODES) return;
    const float4* s4 = (const float4*)(sup + (size_t)i * FDIM);
    float  s[FDIM];
    float4 acc[16];
#pragma unroll
    for (int g = 0; g < 16; ++g) {
        float4 a = s4[g];
        s[4 * g + 0] = a.x; s[4 * g + 1] = a.y; s[4 * g + 2] = a.z; s[4 * g + 3] = a.w;
        acc[g] = make_float4(0.f, 0.f, 0.f, 0.f);
    }
#pragma unroll
    for (int k = 0; k < FDIM; ++k) {
        float sk = s[k];
        const float4* w4 = (const float4*)(W + k * FDIM);  // wave-uniform -> s_load
#pragma unroll
        for (int g = 0; g < 16; ++g) {
            float4 w = w4[g];
            acc[g].x += sk * w.x;
            acc[g].y += sk * w.y;
            acc[g].z += sk * w.z;
            acc[g].w += sk * w.w;
        }
    }
    float4* o4 = (float4*)(out + (size_t)i * FDIM);
#pragma unroll
    for (int g = 0; g < 16; ++g) {
        float4 r;
        r.x = fmaxf(BETA * acc[g].x + (1.0f - BETA) * s[4 * g + 0], 0.0f);
        r.y = fmaxf(BETA * acc[g].y + (1.0f - BETA) * s[4 * g + 1], 0.0f);
        r.z = fmaxf(BETA * acc[g].z + (1.0f - BETA) * s[4 * g + 2], 0.0f);
        r.w = fmaxf(BETA * acc[g].w + (1.0f - BETA) * s[4 * g + 3], 0.0f);
        o4[g] = r;
    }
}

extern "C" void kernel_launch(void* const* d_in, const int* in_sizes, int n_in,
                              void* d_out, int out_size, void* d_ws, size_t ws_size,
                              hipStream_t stream) {
    const float* features  = (const float*)d_in[0];
    const float* features0 = (const float*)d_in[1];
    const int*   edge_src  = (const int*)d_in[2];
    const int*   edge_dst  = (const int*)d_in[3];
    const float* edge_vals = (const float*)d_in[4];
    const float* W         = (const float*)d_in[5];
    float*       out       = (float*)d_out;

    char* ws = (char*)d_ws;
    int*   deg    = (int*)(ws + OFF_DEG);
    int*   offs   = (int*)(ws + OFF_OFFS);
    int*   cursor = (int*)(ws + OFF_CURSOR);
    int*   bsum   = (int*)(ws + OFF_BSUM);
    int*   boff   = (int*)(ws + OFF_BOFF);
    int*   bsrc   = (int*)(ws + OFF_BSRC);
    float* bval   = (float*)(ws + OFF_BVAL);
    float* sup    = (float*)(ws + OFF_SUP);

    hipMemsetAsync(deg, 0, N_NODES * sizeof(int), stream);

    int eblocks = (N_EDGES + 255) / 256;
    k_hist<<<eblocks, 256, 0, stream>>>(edge_dst, deg);
    k_scan1<<<SCAN_BLOCKS, 256, 0, stream>>>(deg, bsum);
    k_scan2<<<1, 512, 0, stream>>>(bsum, boff);
    k_scan3<<<SCAN_BLOCKS, 256, 0, stream>>>(deg, boff, offs, cursor);
    k_bin<<<eblocks, 256, 0, stream>>>(edge_src, edge_dst, edge_vals, cursor, bsrc, bval);

    int gthreads = N_NODES * 64;
    k_gather<<<(gthreads + 255) / 256, 256, 0, stream>>>(offs, bsrc, bval, features, features0, sup);
    k_out<<<(N_NODES + 255) / 256, 256, 0, stream>>>(sup, W, out);
}

// Round 2
// 362.738 us; speedup vs baseline: 1.1277x; 1.1277x over previous
//
#include <hip/hip_runtime.h>

// Problem constants (fixed by reference)
#define N_NODES 100000
#define N_EDGES 1000000
#define FDIM    64
#define ALPHA   0.1f
#define BETA    0.5f

#define SCAN_BLOCKS 391   // ceil(N_NODES/256)

// ws layout (byte offsets). Total ~36.1 MB.
#define OFF_DEG     0u          // N_NODES ints
#define OFF_OFFS    524288u     // N_NODES ints
#define OFF_CURSOR  1048576u    // N_NODES ints
#define OFF_BSUM    1572864u    // SCAN_BLOCKS ints
#define OFF_BOFF    1703936u    // SCAN_BLOCKS ints
#define OFF_BPACK   2097152u    // N_EDGES int2 (8 MB)
#define OFF_G       10485760u   // N_NODES*FDIM floats (25.6 MB)

__global__ void k_hist(const int* __restrict__ dst, int* __restrict__ deg) {
    int e = blockIdx.x * blockDim.x + threadIdx.x;
    if (e < N_EDGES) atomicAdd(&deg[dst[e]], 1);
}

__global__ void k_scan1(const int* __restrict__ deg, int* __restrict__ bsum) {
    __shared__ int lds[256];
    int i = blockIdx.x * 256 + threadIdx.x;
    int v = (i < N_NODES) ? deg[i] : 0;
    lds[threadIdx.x] = v;
    __syncthreads();
    for (int s = 128; s > 0; s >>= 1) {
        if (threadIdx.x < s) lds[threadIdx.x] += lds[threadIdx.x + s];
        __syncthreads();
    }
    if (threadIdx.x == 0) bsum[blockIdx.x] = lds[0];
}

// single block, 512 threads: exclusive scan of SCAN_BLOCKS block sums
__global__ void k_scan2(const int* __restrict__ bsum, int* __restrict__ boff) {
    __shared__ int lds[512];
    int t = threadIdx.x;
    int v = (t < SCAN_BLOCKS) ? bsum[t] : 0;
    lds[t] = v;
    __syncthreads();
    for (int off = 1; off < 512; off <<= 1) {
        int add = (t >= off) ? lds[t - off] : 0;
        __syncthreads();
        lds[t] += add;
        __syncthreads();
    }
    if (t < SCAN_BLOCKS) boff[t] = lds[t] - v;  // exclusive
}

__global__ void k_scan3(const int* __restrict__ deg, const int* __restrict__ boff,
                        int* __restrict__ offs, int* __restrict__ cursor) {
    __shared__ int lds[256];
    int t = threadIdx.x;
    int i = blockIdx.x * 256 + t;
    int v = (i < N_NODES) ? deg[i] : 0;
    lds[t] = v;
    __syncthreads();
    for (int off = 1; off < 256; off <<= 1) {
        int add = (t >= off) ? lds[t - off] : 0;
        __syncthreads();
        lds[t] += add;
        __syncthreads();
    }
    int excl = lds[t] - v + boff[blockIdx.x];
    if (i < N_NODES) { offs[i] = excl; cursor[i] = excl; }
}

__global__ void k_bin(const int* __restrict__ src, const int* __restrict__ dst,
                      const float* __restrict__ val, int* __restrict__ cursor,
                      int2* __restrict__ bpack) {
    int e = blockIdx.x * blockDim.x + threadIdx.x;
    if (e >= N_EDGES) return;
    int d = dst[e];
    int p = atomicAdd(&cursor[d], 1);
    bpack[p] = make_int2(src[e], __float_as_int(val[e]));  // one 8B store
}

// rows 0..N-1:      g = 0.5*(feat@W) + 0.5*feat            (into ws)
// rows N..2N-1:     h = 0.05*(f0@W)  + 0.05*f0             (into d_out)
__global__ void k_mm(const float* __restrict__ feat, const float* __restrict__ f0,
                     const float* __restrict__ W, float* __restrict__ g,
                     float* __restrict__ h) {
    int r = blockIdx.x * blockDim.x + threadIdx.x;
    if (r >= 2 * N_NODES) return;
    bool second = r >= N_NODES;
    int row = second ? r - N_NODES : r;
    const float* x = (second ? f0 : feat) + (size_t)row * FDIM;
    float*       y = (second ? h  : g)   + (size_t)row * FDIM;
    float        a = second ? 0.05f : 0.5f;

    const float4* x4 = (const float4*)x;
    float  s[FDIM];
    float4 acc[16];
#pragma unroll
    for (int q = 0; q < 16; ++q) {
        float4 t = x4[q];
        s[4 * q + 0] = t.x; s[4 * q + 1] = t.y; s[4 * q + 2] = t.z; s[4 * q + 3] = t.w;
        acc[q] = make_float4(0.f, 0.f, 0.f, 0.f);
    }
#pragma unroll
    for (int k = 0; k < FDIM; ++k) {
        float sk = s[k];
        const float4* w4 = (const float4*)(W + k * FDIM);  // wave-uniform -> s_load
#pragma unroll
        for (int q = 0; q < 16; ++q) {
            float4 w = w4[q];
            acc[q].x += sk * w.x;
            acc[q].y += sk * w.y;
            acc[q].z += sk * w.z;
            acc[q].w += sk * w.w;
        }
    }
    float4* y4 = (float4*)y;
#pragma unroll
    for (int q = 0; q < 16; ++q) {
        float4 rr;
        rr.x = a * acc[q].x + a * s[4 * q + 0];
        rr.y = a * acc[q].y + a * s[4 * q + 1];
        rr.z = a * acc[q].z + a * s[4 * q + 2];
        rr.w = a * acc[q].w + a * s[4 * q + 3];
        y4[q] = rr;
    }
}

// one wave per node; lane = feature. out[i] = relu(0.9 * sum_e v*g[src] + out[i])
// (out already holds h = 0.1*(f0@M) from k_mm). Unroll-4 for memory-level parallelism.
__global__ void k_gather(const int* __restrict__ offs, const int2* __restrict__ bpack,
                         const float* __restrict__ g, float* __restrict__ out) {
    int gid  = blockIdx.x * blockDim.x + threadIdx.x;
    int node = gid >> 6;
    int lane = threadIdx.x & 63;
    if (node >= N_NODES) return;
    int beg = offs[node];
    int end = (node == N_NODES - 1) ? N_EDGES : offs[node + 1];
    float acc = 0.0f;
    int e = beg;
    for (; e + 4 <= end; e += 4) {
        int2 p0 = bpack[e + 0];   // wave-uniform, contiguous -> scalar dwordx8
        int2 p1 = bpack[e + 1];
        int2 p2 = bpack[e + 2];
        int2 p3 = bpack[e + 3];
        float f0v = g[(size_t)p0.x * FDIM + lane];  // 4 independent loads in flight
        float f1v = g[(size_t)p1.x * FDIM + lane];
        float f2v = g[(size_t)p2.x * FDIM + lane];
        float f3v = g[(size_t)p3.x * FDIM + lane];
        acc += __int_as_float(p0.y) * f0v;
        acc += __int_as_float(p1.y) * f1v;
        acc += __int_as_float(p2.y) * f2v;
        acc += __int_as_float(p3.y) * f3v;
    }
    for (; e < end; ++e) {
        int2 p = bpack[e];
        acc += __int_as_float(p.y) * g[(size_t)p.x * FDIM + lane];
    }
    size_t oi = (size_t)node * FDIM + lane;
    out[oi] = fmaxf(0.9f * acc + out[oi], 0.0f);
}

extern "C" void kernel_launch(void* const* d_in, const int* in_sizes, int n_in,
                              void* d_out, int out_size, void* d_ws, size_t ws_size,
                              hipStream_t stream) {
    const float* features  = (const float*)d_in[0];
    const float* features0 = (const float*)d_in[1];
    const int*   edge_src  = (const int*)d_in[2];
    const int*   edge_dst  = (const int*)d_in[3];
    const float* edge_vals = (const float*)d_in[4];
    const float* W         = (const float*)d_in[5];
    float*       out       = (float*)d_out;

    char* ws = (char*)d_ws;
    int*   deg    = (int*)(ws + OFF_DEG);
    int*   offs   = (int*)(ws + OFF_OFFS);
    int*   cursor = (int*)(ws + OFF_CURSOR);
    int*   bsum   = (int*)(ws + OFF_BSUM);
    int*   boff   = (int*)(ws + OFF_BOFF);
    int2*  bpack  = (int2*)(ws + OFF_BPACK);
    float* g      = (float*)(ws + OFF_G);

    hipMemsetAsync(deg, 0, N_NODES * sizeof(int), stream);

    int eblocks = (N_EDGES + 255) / 256;
    k_hist<<<eblocks, 256, 0, stream>>>(edge_dst, deg);
    k_scan1<<<SCAN_BLOCKS, 256, 0, stream>>>(deg, bsum);
    k_scan2<<<1, 512, 0, stream>>>(bsum, boff);
    k_scan3<<<SCAN_BLOCKS, 256, 0, stream>>>(deg, boff, offs, cursor);
    k_bin<<<eblocks, 256, 0, stream>>>(edge_src, edge_dst, edge_vals, cursor, bpack);

    int mmblocks = (2 * N_NODES + 255) / 256;
    k_mm<<<mmblocks, 256, 0, stream>>>(features, features0, W, g, out);

    int gthreads = N_NODES * 64;
    k_gather<<<(gthreads + 255) / 256, 256, 0, stream>>>(offs, bpack, g, out);
}